// Round 16
// baseline (270.932 us; speedup 1.0000x reference)
//
#include <hip/hip_runtime.h>
#include <math.h>

__device__ __forceinline__ float rcp_(float x) { return __fdividef(1.0f, x); }

// tanh via [9/8] continued-fraction Pade, t = x^2; 1 rcp, no exp.
__device__ __forceinline__ float tanh_(float x) {
    float t = x * x;
    float p = t + 378.0f;
    p = fmaf(p, t, 17325.0f);
    p = fmaf(p, t, 135135.0f);
    float q = fmaf(28.0f, t, 3150.0f);
    q = fmaf(q, t, 62370.0f);
    q = fmaf(q, t, 135135.0f);
    float r = (x * p) * rcp_(q);
    return fminf(fmaxf(r, -1.0f), 1.0f);
}

// EXACT: softplus(softplus(x)) = log(2 + e^x)
__device__ __forceinline__ float sp2_(float x) {
    return __logf(2.0f + __expf(x));
}

// w[k] = 0.001 + 0.995*softmax(6*softmax(o))[k]; shift-invariance -> no max needed
__device__ __forceinline__ void dsm5_(float o0, float o1, float o2, float o3, float o4,
                                      float* __restrict__ w) {
    float e0 = __expf(o0), e1 = __expf(o1), e2 = __expf(o2),
          e3 = __expf(o3), e4 = __expf(o4);
    float inv = 6.0f * rcp_(((e0 + e1) + (e2 + e3)) + e4);
    float f0 = __expf(e0 * inv);
    float f1 = __expf(e1 * inv);
    float f2 = __expf(e2 * inv);
    float f3 = __expf(e3 * inv);
    float f4 = __expf(e4 * inv);
    float t = 0.995f * rcp_(((f0 + f1) + (f2 + f3)) + f4);
    w[0] = fmaf(f0, t, 0.001f);
    w[1] = fmaf(f1, t, 0.001f);
    w[2] = fmaf(f2, t, 0.001f);
    w[3] = fmaf(f3, t, 0.001f);
    w[4] = fmaf(f4, t, 0.001f);
}

// One thread = one sample, all 8 dims serial; jd is a uniform loop counter so
// ALL waves on a CU walk the SAME ~4.3KB weight stream (scalar-K$ resident).
// Inputs live in registers across the whole jd loop; no LDS, no syncs.
__global__ __launch_bounds__(512)
void nsf_kernel(const float* __restrict__ x_inp, const float* __restrict__ cond_inp,
                const float* __restrict__ Wi1, const float* __restrict__ bi1,
                const float* __restrict__ Wi2, const float* __restrict__ bi2,
                const float* __restrict__ Wi3, const float* __restrict__ bi3,
                const float* __restrict__ Wf1, const float* __restrict__ bf1,
                const float* __restrict__ Wf2, const float* __restrict__ bf2,
                const float* __restrict__ Wf3, const float* __restrict__ bf3,
                float* __restrict__ out, int N)
{
    int s = blockIdx.x * 512 + threadIdx.x;
    int sl = (s < N) ? s : (N - 1);

    // ---- per-sample inputs, loaded ONCE ----
    float c16[16];
    {
        const float4* cp = (const float4*)(cond_inp + (size_t)sl * 16);
        float4 c0 = cp[0], c1 = cp[1], c2 = cp[2], c3 = cp[3];
        c16[0]=c0.x;  c16[1]=c0.y;  c16[2]=c0.z;  c16[3]=c0.w;
        c16[4]=c1.x;  c16[5]=c1.y;  c16[6]=c1.z;  c16[7]=c1.w;
        c16[8]=c2.x;  c16[9]=c2.y;  c16[10]=c2.z; c16[11]=c2.w;
        c16[12]=c3.x; c16[13]=c3.y; c16[14]=c3.z; c16[15]=c3.w;
    }
    float xv[8];
    {
        const float4* xp = (const float4*)(x_inp + (size_t)sl * 8);
        float4 a = xp[0], b = xp[1];
        xv[0]=a.x; xv[1]=a.y; xv[2]=a.z; xv[3]=a.w;
        xv[4]=b.x; xv[5]=b.y; xv[6]=b.z; xv[7]=b.w;
    }

    float total = 0.0f;

#pragma unroll 1
    for (int jd = 0; jd < 8; ++jd) {
        // cond tail + xcur via static-index selects (jd uniform)
        float cond[23];
#pragma unroll
        for (int c = 0; c < 16; ++c) cond[c] = c16[c];
#pragma unroll
        for (int t = 0; t < 7; ++t)
            cond[16 + t] = (t < jd) ? xv[t] : 0.0f;
        float xcur = xv[0];
#pragma unroll
        for (int t = 1; t < 8; ++t) xcur = (jd == t) ? xv[t] : xcur;

        // ---------- gaussian-base network ----------
        float g0, g1;
        {
            const float* W1 = Wi1 + (size_t)jd * 184;
            const float* b1 = bi1 + jd * 8;
            const float* W2 = Wi2 + (size_t)jd * 64;
            const float* b2 = bi2 + jd * 8;
            const float* W3 = Wi3 + (size_t)jd * 16;
            const float* b3 = bi3 + jd * 2;
            float h1[8], h2[8];
#pragma unroll
            for (int i = 0; i < 8; ++i) {
                float a = b1[i];
#pragma unroll
                for (int c = 0; c < 23; ++c) a = fmaf(W1[i * 23 + c], cond[c], a);
                h1[i] = tanh_(a);
            }
#pragma unroll
            for (int i = 0; i < 8; ++i) {
                float a = b2[i];
#pragma unroll
                for (int c = 0; c < 8; ++c) a = fmaf(W2[i * 8 + c], h1[c], a);
                h2[i] = tanh_(a);
            }
            g0 = b3[0]; g1 = b3[1];
#pragma unroll
            for (int c = 0; c < 8; ++c) {
                g0 = fmaf(W3[c], h2[c], g0);
                g1 = fmaf(W3[8 + c], h2[c], g1);
            }
        }

        // ---------- flows ----------
        float ldsum = 0.0f;
#pragma unroll
        for (int jf = 0; jf < 2; ++jf) {
            const int nf = jd * 2 + jf;
            const float* F1  = Wf1 + (size_t)nf * 184;
            const float* fb1 = bf1 + nf * 8;
            const float* F2  = Wf2 + (size_t)nf * 64;
            const float* fb2 = bf2 + nf * 8;
            const float* F3  = Wf3 + (size_t)nf * 112;
            const float* fb3 = bf3 + nf * 14;

            float h1[8], h2[8];
#pragma unroll
            for (int i = 0; i < 8; ++i) {
                float a = fb1[i];
#pragma unroll
                for (int c = 0; c < 23; ++c) a = fmaf(F1[i * 23 + c], cond[c], a);
                h1[i] = tanh_(a);
            }
#pragma unroll
            for (int i = 0; i < 8; ++i) {
                float a = fb2[i];
#pragma unroll
                for (int c = 0; c < 8; ++c) a = fmaf(F2[i * 8 + c], h1[c], a);
                h2[i] = tanh_(a);
            }
            float o[14];
#pragma unroll
            for (int i = 0; i < 14; ++i) {
                float a = fb3[i];
#pragma unroll
                for (int c = 0; c < 8; ++c) a = fmaf(F3[i * 8 + c], h2[c], a);
                o[i] = a;
            }

            // ---------- RQS spline ----------
            float wv[5], hv[5];
            dsm5_(o[0], o[1], o[2], o[3], o[4], wv);
            dsm5_(o[5], o[6], o[7], o[8], o[9], hv);
            float di1 = sp2_(o[10]) + 0.001f;
            float di2 = sp2_(o[11]) + 0.001f;
            float di3 = sp2_(o[12]) + 0.001f;
            float di4 = sp2_(o[13]) + 0.001f;

            float xc = fminf(fmaxf(xcur, -3.0f), 3.0f);

            float runw = wv[0], runh = hv[0];
            float cwL = -3.0f, chL = -3.0f;
            float cwR = fmaf(6.0f, runw, -3.0f);
            float chR = fmaf(6.0f, runh, -3.0f);
            float icw = cwL, ibw = cwR - cwL, ich = chL, ihh = chR - chL;
            float d0 = 1.0f, d1 = di1;
#pragma unroll
            for (int k = 1; k < 5; ++k) {
                cwL = cwR; chL = chR;
                runw += wv[k]; runh += hv[k];
                cwR = (k == 4) ? 3.0f : fmaf(6.0f, runw, -3.0f);
                chR = (k == 4) ? 3.0f : fmaf(6.0f, runh, -3.0f);
                float dk0 = (k == 1) ? di1 : (k == 2) ? di2 : (k == 3) ? di3 : di4;
                float dk1 = (k == 1) ? di2 : (k == 2) ? di3 : (k == 3) ? di4 : 1.0f;
                bool sel = (xc >= cwL);
                icw = sel ? cwL : icw;
                ibw = sel ? (cwR - cwL) : ibw;
                ich = sel ? chL : ich;
                ihh = sel ? (chR - chL) : ihh;
                d0  = sel ? dk0 : d0;
                d1  = sel ? dk1 : d1;
            }

            float rb     = rcp_(ibw);
            float idelta = ihh * rb;
            float th     = (xc - icw) * rb;
            float t2     = th * th;
            float omt    = 1.0f - th;
            float tomt   = th * omt;
            float den    = fmaf(fmaf(-2.0f, idelta, d0 + d1), tomt, idelta);
            float rden   = rcp_(den);
            float xn     = fmaf(ihh * fmaf(idelta, t2, d0 * tomt), rden, ich);
            float num    = (idelta * idelta) *
                           fmaf(d1, t2, fmaf(idelta + idelta, tomt, d0 * (omt * omt)));
            float ldi    = __logf((num * rden) * rden);

            bool inside = (xcur >= -3.0f) && (xcur <= 3.0f);
            xcur  = inside ? xn : xcur;
            ldsum = inside ? (ldsum + ldi) : ldsum;
        }

        // ---------- gaussian base log-prob ----------
        float z  = (xcur - g0) * __expf(-g1);
        float ez = __expf(-z);
        float lp = -(z + ez) - g1;
        if (isnan(lp) || isinf(lp)) lp = -100.0f;
        total += ldsum + lp;
    }

    if (s < N) out[s] = total;
}

extern "C" void kernel_launch(void* const* d_in, const int* in_sizes, int n_in,
                              void* d_out, int out_size, void* d_ws, size_t ws_size,
                              hipStream_t stream) {
    const float* x_inp    = (const float*)d_in[0];
    const float* cond_inp = (const float*)d_in[1];
    const float* Wi1 = (const float*)d_in[2];
    const float* bi1 = (const float*)d_in[3];
    const float* Wi2 = (const float*)d_in[4];
    const float* bi2 = (const float*)d_in[5];
    const float* Wi3 = (const float*)d_in[6];
    const float* bi3 = (const float*)d_in[7];
    const float* Wf1 = (const float*)d_in[8];
    const float* bf1 = (const float*)d_in[9];
    const float* Wf2 = (const float*)d_in[10];
    const float* bf2 = (const float*)d_in[11];
    const float* Wf3 = (const float*)d_in[12];
    const float* bf3 = (const float*)d_in[13];
    float* out = (float*)d_out;

    int N = out_size;
    int grid = (N + 511) / 512;
    hipLaunchKernelGGL(nsf_kernel, dim3(grid), dim3(512), 0, stream,
                       x_inp, cond_inp, Wi1, bi1, Wi2, bi2, Wi3, bi3,
                       Wf1, bf1, Wf2, bf2, Wf3, bf3, out, N);
}

// Round 17
// 235.192 us; speedup vs baseline: 1.1520x; 1.1520x over previous
//
#include <hip/hip_runtime.h>
#include <math.h>

__device__ __forceinline__ float rcp_(float x) { return __fdividef(1.0f, x); }

// tanh via exp: 3 VALU + 2 trans (vs Pade's 8 VALU + 1 trans).
// VALU pipe is the saturated resource; trans pipe co-issues and is ~idle.
// Exact at extremes: x->+inf e=inf -> 1; x->-inf e=0 -> -1.
__device__ __forceinline__ float tanh_(float x) {
    float e = __expf(x + x);
    return 1.0f - 2.0f * rcp_(e + 1.0f);
}

// EXACT: softplus(softplus(x)) = log(2 + e^x)
__device__ __forceinline__ float sp2_(float x) {
    return __logf(2.0f + __expf(x));
}

// w[k] = 0.001 + 0.995*softmax(6*softmax(o))[k]; shift-invariance -> no max needed
__device__ __forceinline__ void dsm5_(float o0, float o1, float o2, float o3, float o4,
                                      float* __restrict__ w) {
    float e0 = __expf(o0), e1 = __expf(o1), e2 = __expf(o2),
          e3 = __expf(o3), e4 = __expf(o4);
    float inv = 6.0f * rcp_(((e0 + e1) + (e2 + e3)) + e4);
    float f0 = __expf(e0 * inv);
    float f1 = __expf(e1 * inv);
    float f2 = __expf(e2 * inv);
    float f3 = __expf(e3 * inv);
    float f4 = __expf(e4 * inv);
    float t = 0.995f * rcp_(((f0 + f1) + (f2 + f3)) + f4);
    w[0] = fmaf(f0, t, 0.001f);
    w[1] = fmaf(f1, t, 0.001f);
    w[2] = fmaf(f2, t, 0.001f);
    w[3] = fmaf(f3, t, 0.001f);
    w[4] = fmaf(f4, t, 0.001f);
}

__global__ __launch_bounds__(512) __attribute__((amdgpu_waves_per_eu(5, 8)))
void nsf_kernel(const float* __restrict__ x_inp, const float* __restrict__ cond_inp,
                const float* __restrict__ Wi1, const float* __restrict__ bi1,
                const float* __restrict__ Wi2, const float* __restrict__ bi2,
                const float* __restrict__ Wi3, const float* __restrict__ bi3,
                const float* __restrict__ Wf1, const float* __restrict__ bf1,
                const float* __restrict__ Wf2, const float* __restrict__ bf2,
                const float* __restrict__ Wf3, const float* __restrict__ bf3,
                float* __restrict__ out, int N)
{
    const int lane = threadIdx.x;                 // 0..63  -> sample within block
    const int jd   = threadIdx.y;                 // 0..7   -> dim (one wave per dim)
    const int jdu  = __builtin_amdgcn_readfirstlane(jd);  // wave-uniform weight addrs
    int s = blockIdx.x * 64 + lane;
    int sl = (s < N) ? s : (N - 1);               // clamp for safe loads; store guarded

    // ---- per-sample inputs ----
    float cond[23];
    float xcur;
    {
        const float4* cp = (const float4*)(cond_inp + (size_t)sl * 16);
        float4 c0 = cp[0], c1 = cp[1], c2 = cp[2], c3 = cp[3];
        cond[0]=c0.x;  cond[1]=c0.y;  cond[2]=c0.z;  cond[3]=c0.w;
        cond[4]=c1.x;  cond[5]=c1.y;  cond[6]=c1.z;  cond[7]=c1.w;
        cond[8]=c2.x;  cond[9]=c2.y;  cond[10]=c2.z; cond[11]=c2.w;
        cond[12]=c3.x; cond[13]=c3.y; cond[14]=c3.z; cond[15]=c3.w;

        const float4* xp = (const float4*)(x_inp + (size_t)sl * 8);
        float4 a = xp[0], b = xp[1];
        float xv[8] = {a.x, a.y, a.z, a.w, b.x, b.y, b.z, b.w};
#pragma unroll
        for (int t = 0; t < 7; ++t)
            cond[16 + t] = (t < jd) ? xv[t] : 0.0f;
        xcur = xv[0];
#pragma unroll
        for (int t = 1; t < 8; ++t) xcur = (jd == t) ? xv[t] : xcur;
    }

    // ---------- gaussian-base network ----------
    float g0, g1;
    {
        const float* W1 = Wi1 + (size_t)jdu * 184;
        const float* b1 = bi1 + jdu * 8;
        const float* W2 = Wi2 + (size_t)jdu * 64;
        const float* b2 = bi2 + jdu * 8;
        const float* W3 = Wi3 + (size_t)jdu * 16;
        const float* b3 = bi3 + jdu * 2;
        float h1[8], h2[8];
#pragma unroll
        for (int i = 0; i < 8; ++i) {
            float a = b1[i];
#pragma unroll
            for (int c = 0; c < 23; ++c) a = fmaf(W1[i * 23 + c], cond[c], a);
            h1[i] = tanh_(a);
        }
#pragma unroll
        for (int i = 0; i < 8; ++i) {
            float a = b2[i];
#pragma unroll
            for (int c = 0; c < 8; ++c) a = fmaf(W2[i * 8 + c], h1[c], a);
            h2[i] = tanh_(a);
        }
        g0 = b3[0]; g1 = b3[1];
#pragma unroll
        for (int c = 0; c < 8; ++c) {
            g0 = fmaf(W3[c], h2[c], g0);
            g1 = fmaf(W3[8 + c], h2[c], g1);
        }
    }

    // ---------- flows ----------
    float ldsum = 0.0f;
#pragma unroll
    for (int jf = 0; jf < 2; ++jf) {
        const int nf = jdu * 2 + jf;
        const float* F1  = Wf1 + (size_t)nf * 184;
        const float* fb1 = bf1 + nf * 8;
        const float* F2  = Wf2 + (size_t)nf * 64;
        const float* fb2 = bf2 + nf * 8;
        const float* F3  = Wf3 + (size_t)nf * 112;
        const float* fb3 = bf3 + nf * 14;

        float h1[8], h2[8];
#pragma unroll
        for (int i = 0; i < 8; ++i) {
            float a = fb1[i];
#pragma unroll
            for (int c = 0; c < 23; ++c) a = fmaf(F1[i * 23 + c], cond[c], a);
            h1[i] = tanh_(a);
        }
#pragma unroll
        for (int i = 0; i < 8; ++i) {
            float a = fb2[i];
#pragma unroll
            for (int c = 0; c < 8; ++c) a = fmaf(F2[i * 8 + c], h1[c], a);
            h2[i] = tanh_(a);
        }
        float o[14];
#pragma unroll
        for (int i = 0; i < 14; ++i) {
            float a = fb3[i];
#pragma unroll
            for (int c = 0; c < 8; ++c) a = fmaf(F3[i * 8 + c], h2[c], a);
            o[i] = a;
        }

        // ---------- RQS spline ----------
        float wv[5], hv[5];
        dsm5_(o[0], o[1], o[2], o[3], o[4], wv);
        dsm5_(o[5], o[6], o[7], o[8], o[9], hv);
        float di1 = sp2_(o[10]) + 0.001f;
        float di2 = sp2_(o[11]) + 0.001f;
        float di3 = sp2_(o[12]) + 0.001f;
        float di4 = sp2_(o[13]) + 0.001f;

        float xc = fminf(fmaxf(xcur, -3.0f), 3.0f);

        float runw = wv[0], runh = hv[0];
        float cwL = -3.0f, chL = -3.0f;
        float cwR = fmaf(6.0f, runw, -3.0f);
        float chR = fmaf(6.0f, runh, -3.0f);
        float icw = cwL, ibw = cwR - cwL, ich = chL, ihh = chR - chL;
        float d0 = 1.0f, d1 = di1;
#pragma unroll
        for (int k = 1; k < 5; ++k) {
            cwL = cwR; chL = chR;
            runw += wv[k]; runh += hv[k];
            cwR = (k == 4) ? 3.0f : fmaf(6.0f, runw, -3.0f);
            chR = (k == 4) ? 3.0f : fmaf(6.0f, runh, -3.0f);
            float dk0 = (k == 1) ? di1 : (k == 2) ? di2 : (k == 3) ? di3 : di4;
            float dk1 = (k == 1) ? di2 : (k == 2) ? di3 : (k == 3) ? di4 : 1.0f;
            bool sel = (xc >= cwL);
            icw = sel ? cwL : icw;
            ibw = sel ? (cwR - cwL) : ibw;
            ich = sel ? chL : ich;
            ihh = sel ? (chR - chL) : ihh;
            d0  = sel ? dk0 : d0;
            d1  = sel ? dk1 : d1;
        }

        float rb     = rcp_(ibw);
        float idelta = ihh * rb;
        float th     = (xc - icw) * rb;
        float t2     = th * th;
        float omt    = 1.0f - th;
        float tomt   = th * omt;
        float den    = fmaf(fmaf(-2.0f, idelta, d0 + d1), tomt, idelta);
        float rden   = rcp_(den);
        float xn     = fmaf(ihh * fmaf(idelta, t2, d0 * tomt), rden, ich);
        float num    = (idelta * idelta) *
                       fmaf(d1, t2, fmaf(idelta + idelta, tomt, d0 * (omt * omt)));
        float ldi    = __logf((num * rden) * rden);

        bool inside = (xcur >= -3.0f) && (xcur <= 3.0f);
        xcur  = inside ? xn : xcur;
        ldsum = inside ? (ldsum + ldi) : ldsum;
    }

    // ---------- gaussian base log-prob ----------
    float z  = (xcur - g0) * __expf(-g1);
    float ez = __expf(-z);
    float lp = -(z + ez) - g1;
    if (isnan(lp) || isinf(lp)) lp = -100.0f;
    float col = ldsum + lp;

    // ---------- cross-dim reduction (8 waves -> 1 value per sample) ----------
    __shared__ float red[8][64];
    red[jd][lane] = col;
    __syncthreads();
    if (jd == 0 && s < N) {
        float acc = red[0][lane];
#pragma unroll
        for (int j = 1; j < 8; ++j) acc += red[j][lane];
        out[s] = acc;
    }
}

extern "C" void kernel_launch(void* const* d_in, const int* in_sizes, int n_in,
                              void* d_out, int out_size, void* d_ws, size_t ws_size,
                              hipStream_t stream) {
    const float* x_inp    = (const float*)d_in[0];
    const float* cond_inp = (const float*)d_in[1];
    const float* Wi1 = (const float*)d_in[2];
    const float* bi1 = (const float*)d_in[3];
    const float* Wi2 = (const float*)d_in[4];
    const float* bi2 = (const float*)d_in[5];
    const float* Wi3 = (const float*)d_in[6];
    const float* bi3 = (const float*)d_in[7];
    const float* Wf1 = (const float*)d_in[8];
    const float* bf1 = (const float*)d_in[9];
    const float* Wf2 = (const float*)d_in[10];
    const float* bf2 = (const float*)d_in[11];
    const float* Wf3 = (const float*)d_in[12];
    const float* bf3 = (const float*)d_in[13];
    float* out = (float*)d_out;

    int N = out_size;
    int grid = (N + 63) / 64;
    dim3 block(64, 8, 1);
    hipLaunchKernelGGL(nsf_kernel, dim3(grid), block, 0, stream,
                       x_inp, cond_inp, Wi1, bi1, Wi2, bi2, Wi3, bi3,
                       Wf1, bf1, Wf2, bf2, Wf3, bf3, out, N);
}